// Round 2
// baseline (364.732 us; speedup 1.0000x reference)
//
#include <hip/hip_runtime.h>
#include <math.h>

// ---------------------------------------------------------------------------
// Segmented softmax: softmax within each contiguous n-best group.
// scores: float32[TOTAL], nBestIndex: int32[NUM_SEG], out: float32[TOTAL].
// Offsets = exclusive prefix sum of nBestIndex (ragged in general).
//
// R4 design: R3 (16-lane group per segment, register-resident, shfl-reduce)
// was latency-bound at ~3.5 TB/s: per-thread dependent chain
// (offset loads -> addr -> 4 loads) exposed too few in-flight bytes.
// R4 fixes: (a) block-cooperative starts[] table in LDS (one coalesced
// load + barrier replaces per-thread dependent offset loads),
// (b) 4 segments per 16-lane group with all 16 data loads issued before
// any reduction (4x in-flight bytes, interleaved reduction chains).
// Segments with c > 64 fall back to strided 3-pass global path.
// ---------------------------------------------------------------------------

#define GSEG   16                          // lanes per segment group
#define SPG    4                           // segments per group (ILP batch)
#define SBLOCK 256                         // threads per softmax block
#define SEGS_B ((SBLOCK / GSEG) * SPG)     // 64 segments per block

// Kernel A: per-block (256-wide) exclusive scan of counts; block totals out.
__global__ __launch_bounds__(256) void scan_local_kernel(
    const int* __restrict__ counts, int n_seg,
    int* __restrict__ local_scan, int* __restrict__ block_sums) {
    __shared__ int sm[256];
    const int t = threadIdx.x;
    const int g = blockIdx.x * 256 + t;
    const int v = (g < n_seg) ? counts[g] : 0;
    sm[t] = v;
    __syncthreads();
    for (int off = 1; off < 256; off <<= 1) {
        int y = (t >= off) ? sm[t - off] : 0;
        __syncthreads();
        sm[t] += y;
        __syncthreads();
    }
    if (g < n_seg) local_scan[g] = sm[t] - v;   // exclusive within block
    if (t == 255) block_sums[blockIdx.x] = sm[255];
}

// Kernel B: single-block exclusive scan of block_sums in place.
__global__ __launch_bounds__(256) void scan_bsums_kernel(
    int* __restrict__ bsum, int nb) {
    __shared__ int sm[256];
    const int t = threadIdx.x;
    const int per = (nb + 255) >> 8;
    const int beg = t * per;
    const int end = (beg + per < nb) ? beg + per : nb;
    int tot = 0;
    for (int j = beg; j < end; ++j) tot += bsum[j];
    sm[t] = tot;
    __syncthreads();
    for (int off = 1; off < 256; off <<= 1) {
        int y = (t >= off) ? sm[t - off] : 0;
        __syncthreads();
        sm[t] += y;
        __syncthreads();
    }
    int run = sm[t] - tot;
    for (int j = beg; j < end; ++j) {
        int v = bsum[j];
        bsum[j] = run;
        run += v;
    }
}

// Kernel C: register-resident segmented softmax.
// 16 groups of 16 lanes per block; each group owns 4 consecutive segments.
__global__ __launch_bounds__(SBLOCK) void seg_softmax_kernel(
    const float* __restrict__ scores,
    const int* __restrict__ local_scan, const int* __restrict__ bsum,
    float* __restrict__ out, int n_seg, int total) {
    __shared__ int starts[SEGS_B + 1];

    const int tid  = threadIdx.x;
    const int seg0 = blockIdx.x * SEGS_B;

    // Block-cooperative offset table: one coalesced pass, then broadcast
    // from LDS (kills the per-thread dependent offset-load chain of R3).
    if (tid <= SEGS_B) {
        const int s = seg0 + tid;
        starts[tid] = (s < n_seg) ? (local_scan[s] + bsum[s >> 8]) : total;
    }
    __syncthreads();

    const int p   = tid & (GSEG - 1);      // lane within group
    const int grp = tid >> 4;              // group 0..15

    int st[SPG], c[SPG];
    #pragma unroll
    for (int q = 0; q < SPG; ++q) {
        const int ls = grp * SPG + q;      // local segment index 0..63
        st[q] = starts[ls];
        c[q]  = starts[ls + 1] - st[q];
    }

    bool all_small = true;
    #pragma unroll
    for (int q = 0; q < SPG; ++q) all_small &= (c[q] <= 4 * GSEG);

    if (all_small) {
        // ---- fast path: issue ALL 16 data loads up front (in-flight ILP),
        //      then run 4 independent shfl-reduction chains. ----
        float v[SPG][4];
        #pragma unroll
        for (int q = 0; q < SPG; ++q) {
            #pragma unroll
            for (int r = 0; r < 4; ++r) {
                const int idx = p + r * GSEG;
                v[q][r] = (idx < c[q]) ? scores[st[q] + idx] : -INFINITY;
            }
        }

        #pragma unroll
        for (int q = 0; q < SPG; ++q) {
            if (c[q] <= 0) continue;
            float m = fmaxf(fmaxf(v[q][0], v[q][1]), fmaxf(v[q][2], v[q][3]));
            #pragma unroll
            for (int off = 1; off < GSEG; off <<= 1)
                m = fmaxf(m, __shfl_xor(m, off, GSEG));

            // exp(-INF - m) == 0, so inactive slots contribute nothing.
            const float e0 = __expf(v[q][0] - m);
            const float e1 = __expf(v[q][1] - m);
            const float e2 = __expf(v[q][2] - m);
            const float e3 = __expf(v[q][3] - m);
            float s = (e0 + e1) + (e2 + e3);
            #pragma unroll
            for (int off = 1; off < GSEG; off <<= 1)
                s += __shfl_xor(s, off, GSEG);

            const float inv = __builtin_amdgcn_rcpf(s);
            if (p < c[q])             out[st[q] + p]            = e0 * inv;
            if (p + GSEG < c[q])      out[st[q] + p + GSEG]     = e1 * inv;
            if (p + 2 * GSEG < c[q])  out[st[q] + p + 2 * GSEG] = e2 * inv;
            if (p + 3 * GSEG < c[q])  out[st[q] + p + 3 * GSEG] = e3 * inv;
        }
    } else {
        // ---- slow path: strided 3-pass over global memory per segment ----
        #pragma unroll
        for (int q = 0; q < SPG; ++q) {
            if (c[q] <= 0) continue;
            float m = -INFINITY;
            for (int j = p; j < c[q]; j += GSEG)
                m = fmaxf(m, scores[st[q] + j]);
            #pragma unroll
            for (int off = 1; off < GSEG; off <<= 1)
                m = fmaxf(m, __shfl_xor(m, off, GSEG));

            float s = 0.0f;
            for (int j = p; j < c[q]; j += GSEG)
                s += __expf(scores[st[q] + j] - m);
            #pragma unroll
            for (int off = 1; off < GSEG; off <<= 1)
                s += __shfl_xor(s, off, GSEG);

            const float inv = __builtin_amdgcn_rcpf(s);
            for (int j = p; j < c[q]; j += GSEG)
                out[st[q] + j] = __expf(scores[st[q] + j] - m) * inv;
        }
    }
}

extern "C" void kernel_launch(void* const* d_in, const int* in_sizes, int n_in,
                              void* d_out, int out_size, void* d_ws, size_t ws_size,
                              hipStream_t stream) {
    const float* scores = (const float*)d_in[0];
    const int*   counts = (const int*)d_in[1];
    float* out = (float*)d_out;
    const int n_seg = in_sizes[1];
    const int total = in_sizes[0];

    // Workspace layout: [n_seg] local exclusive scan | [nblocksA] block sums
    int* local_scan = (int*)d_ws;
    const int nblocksA = (n_seg + 255) / 256;
    int* block_sums = local_scan + n_seg;

    scan_local_kernel<<<nblocksA, 256, 0, stream>>>(counts, n_seg, local_scan, block_sums);
    scan_bsums_kernel<<<1, 256, 0, stream>>>(block_sums, nblocksA);

    const int nblocksC = (n_seg + SEGS_B - 1) / SEGS_B;
    seg_softmax_kernel<<<nblocksC, SBLOCK, 0, stream>>>(
        scores, local_scan, block_sums, out, n_seg, total);
}

// Round 3
// 351.074 us; speedup vs baseline: 1.0389x; 1.0389x over previous
//
#include <hip/hip_runtime.h>
#include <math.h>

// ---------------------------------------------------------------------------
// Segmented softmax: softmax within each contiguous n-best group.
// scores: float32[TOTAL], nBestIndex: int32[NUM_SEG], out: float32[TOTAL].
// Offsets = exclusive prefix sum of nBestIndex (ragged in general).
//
// R5 design: R2/R3/R4 all plateaued at ~122us / 2.5 TB/s with totally
// different structures. Common factor: scalar-dword global access shape
// (64B chunks at 200-800B strides) -> request-rate-limited, not byte-limited.
// R5 streams the block span with float4 (1KB/wave-instr, line-aligned, like
// the 6.5 TB/s fill kernels) and runs the softmax middle phase wave-parallel
// from LDS: 16-lane group x 4 segments, register values, shfl_xor reductions,
// results written back to LDS, float4 stage-out.
// LDS 13.6KB/block -> 8 blocks/CU -> staging phases overlap across blocks.
// ---------------------------------------------------------------------------

#define GSEG   16                          // lanes per segment group
#define SPG    4                           // segments per group
#define SBLOCK 256                         // threads per softmax block
#define SEGS_B ((SBLOCK / GSEG) * SPG)     // 64 segments per block
#define LDS_FLOATS 3328                    // 13.3 KB span buffer

// Kernel A: per-block (256-wide) exclusive scan of counts; block totals out.
__global__ __launch_bounds__(256) void scan_local_kernel(
    const int* __restrict__ counts, int n_seg,
    int* __restrict__ local_scan, int* __restrict__ block_sums) {
    __shared__ int sm[256];
    const int t = threadIdx.x;
    const int g = blockIdx.x * 256 + t;
    const int v = (g < n_seg) ? counts[g] : 0;
    sm[t] = v;
    __syncthreads();
    for (int off = 1; off < 256; off <<= 1) {
        int y = (t >= off) ? sm[t - off] : 0;
        __syncthreads();
        sm[t] += y;
        __syncthreads();
    }
    if (g < n_seg) local_scan[g] = sm[t] - v;   // exclusive within block
    if (t == 255) block_sums[blockIdx.x] = sm[255];
}

// Kernel B: single-block exclusive scan of block_sums in place.
__global__ __launch_bounds__(256) void scan_bsums_kernel(
    int* __restrict__ bsum, int nb) {
    __shared__ int sm[256];
    const int t = threadIdx.x;
    const int per = (nb + 255) >> 8;
    const int beg = t * per;
    const int end = (beg + per < nb) ? beg + per : nb;
    int tot = 0;
    for (int j = beg; j < end; ++j) tot += bsum[j];
    sm[t] = tot;
    __syncthreads();
    for (int off = 1; off < 256; off <<= 1) {
        int y = (t >= off) ? sm[t - off] : 0;
        __syncthreads();
        sm[t] += y;
        __syncthreads();
    }
    int run = sm[t] - tot;
    for (int j = beg; j < end; ++j) {
        int v = bsum[j];
        bsum[j] = run;
        run += v;
    }
}

// Kernel C: float4-streamed, LDS-resident, wave-parallel segmented softmax.
__global__ __launch_bounds__(SBLOCK) void seg_softmax_kernel(
    const float* __restrict__ scores,
    const int* __restrict__ local_scan, const int* __restrict__ bsum,
    float* __restrict__ out, int n_seg, int total) {
    __shared__ float sm[LDS_FLOATS];
    __shared__ int starts[SEGS_B + 1];

    const int tid  = threadIdx.x;
    const int seg0 = blockIdx.x * SEGS_B;

    // Offset table for the middle phase (coalesced; consumed after barrier).
    if (tid <= SEGS_B) {
        const int s = seg0 + tid;
        starts[tid] = (s < n_seg) ? (local_scan[s] + bsum[s >> 8]) : total;
    }

    // All threads compute base/span redundantly (same-address loads broadcast)
    // so staging can begin without waiting for the starts[] barrier.
    const int base  = local_scan[seg0] + bsum[seg0 >> 8];
    const int eseg  = seg0 + SEGS_B;
    const int bend  = (eseg < n_seg) ? (local_scan[eseg] + bsum[eseg >> 8]) : total;
    const int span  = bend - base;

    if (span <= LDS_FLOATS && (base & 3) == 0) {
        // ---- stage-in: float4, 1KB per wave instruction ----
        const float4* __restrict__ src = (const float4*)(scores + base);
        const int nvec = span >> 2;
        for (int i = tid; i < nvec; i += SBLOCK)
            ((float4*)sm)[i] = src[i];
        for (int i = (nvec << 2) + tid; i < span; i += SBLOCK)
            sm[i] = scores[base + i];
        __syncthreads();

        // ---- middle: 16-lane group x 4 segments, registers + shfl ----
        const int p   = tid & (GSEG - 1);
        const int grp = tid >> 4;

        int st[SPG], c[SPG];
        #pragma unroll
        for (int q = 0; q < SPG; ++q) {
            const int ls = grp * SPG + q;
            st[q] = starts[ls] - base;
            c[q]  = starts[ls + 1] - starts[ls];
        }

        #pragma unroll
        for (int q = 0; q < SPG; ++q) {
            if (c[q] <= 0) continue;
            if (c[q] <= 4 * GSEG) {
                float v0 = -INFINITY, v1 = -INFINITY, v2 = -INFINITY, v3 = -INFINITY;
                const int i0 = p, i1 = p + GSEG, i2 = p + 2 * GSEG, i3 = p + 3 * GSEG;
                if (i0 < c[q]) v0 = sm[st[q] + i0];
                if (i1 < c[q]) v1 = sm[st[q] + i1];
                if (i2 < c[q]) v2 = sm[st[q] + i2];
                if (i3 < c[q]) v3 = sm[st[q] + i3];

                float m = fmaxf(fmaxf(v0, v1), fmaxf(v2, v3));
                #pragma unroll
                for (int off = 1; off < GSEG; off <<= 1)
                    m = fmaxf(m, __shfl_xor(m, off, GSEG));

                const float e0 = __expf(v0 - m);
                const float e1 = __expf(v1 - m);
                const float e2 = __expf(v2 - m);
                const float e3 = __expf(v3 - m);
                float s = (e0 + e1) + (e2 + e3);
                #pragma unroll
                for (int off = 1; off < GSEG; off <<= 1)
                    s += __shfl_xor(s, off, GSEG);

                const float inv = __builtin_amdgcn_rcpf(s);
                if (i0 < c[q]) sm[st[q] + i0] = e0 * inv;
                if (i1 < c[q]) sm[st[q] + i1] = e1 * inv;
                if (i2 < c[q]) sm[st[q] + i2] = e2 * inv;
                if (i3 < c[q]) sm[st[q] + i3] = e3 * inv;
            } else {
                // rare big segment, still LDS-resident: strided 3-pass
                float m = -INFINITY;
                for (int j = p; j < c[q]; j += GSEG)
                    m = fmaxf(m, sm[st[q] + j]);
                #pragma unroll
                for (int off = 1; off < GSEG; off <<= 1)
                    m = fmaxf(m, __shfl_xor(m, off, GSEG));
                float s = 0.0f;
                for (int j = p; j < c[q]; j += GSEG) {
                    const float e = __expf(sm[st[q] + j] - m);
                    sm[st[q] + j] = e;
                    s += e;
                }
                #pragma unroll
                for (int off = 1; off < GSEG; off <<= 1)
                    s += __shfl_xor(s, off, GSEG);
                const float inv = __builtin_amdgcn_rcpf(s);
                for (int j = p; j < c[q]; j += GSEG)
                    sm[st[q] + j] *= inv;
            }
        }
        __syncthreads();

        // ---- stage-out: float4 ----
        float4* __restrict__ dst = (float4*)(out + base);
        for (int i = tid; i < nvec; i += SBLOCK)
            dst[i] = ((const float4*)sm)[i];
        for (int i = (nvec << 2) + tid; i < span; i += SBLOCK)
            out[base + i] = sm[i];
    } else {
        // ---- slow path: span too big / unaligned -> strided global 3-pass ----
        __syncthreads();   // starts[] ready; branch is block-uniform
        const int p   = tid & (GSEG - 1);
        const int grp = tid >> 4;
        #pragma unroll
        for (int q = 0; q < SPG; ++q) {
            const int ls = grp * SPG + q;
            const int st = starts[ls];
            const int c  = starts[ls + 1] - st;
            if (c <= 0) continue;
            float m = -INFINITY;
            for (int j = p; j < c; j += GSEG)
                m = fmaxf(m, scores[st + j]);
            #pragma unroll
            for (int off = 1; off < GSEG; off <<= 1)
                m = fmaxf(m, __shfl_xor(m, off, GSEG));
            float s = 0.0f;
            for (int j = p; j < c; j += GSEG)
                s += __expf(scores[st + j] - m);
            #pragma unroll
            for (int off = 1; off < GSEG; off <<= 1)
                s += __shfl_xor(s, off, GSEG);
            const float inv = __builtin_amdgcn_rcpf(s);
            for (int j = p; j < c; j += GSEG)
                out[st + j] = __expf(scores[st + j] - m) * inv;
        }
    }
}

extern "C" void kernel_launch(void* const* d_in, const int* in_sizes, int n_in,
                              void* d_out, int out_size, void* d_ws, size_t ws_size,
                              hipStream_t stream) {
    const float* scores = (const float*)d_in[0];
    const int*   counts = (const int*)d_in[1];
    float* out = (float*)d_out;
    const int n_seg = in_sizes[1];
    const int total = in_sizes[0];

    // Workspace layout: [n_seg] local exclusive scan | [nblocksA] block sums
    int* local_scan = (int*)d_ws;
    const int nblocksA = (n_seg + 255) / 256;
    int* block_sums = local_scan + n_seg;

    scan_local_kernel<<<nblocksA, 256, 0, stream>>>(counts, n_seg, local_scan, block_sums);
    scan_bsums_kernel<<<1, 256, 0, stream>>>(block_sums, nblocksA);

    const int nblocksC = (n_seg + SEGS_B - 1) / SEGS_B;
    seg_softmax_kernel<<<nblocksC, SBLOCK, 0, stream>>>(
        scores, local_scan, block_sums, out, n_seg, total);
}

// Round 4
// 350.691 us; speedup vs baseline: 1.0400x; 1.0011x over previous
//
#include <hip/hip_runtime.h>
#include <math.h>

// ---------------------------------------------------------------------------
// Segmented softmax: softmax within each contiguous n-best group.
// scores: float32[TOTAL], nBestIndex: int32[NUM_SEG], out: float32[TOTAL].
// Offsets = exclusive prefix sum of nBestIndex (ragged in general).
//
// R6: R2-R5 all plateaued ~115-125us at ~2.5 TB/s with zero saturated pipes
// -> duty-cycle problem: blocks had no reads in flight during middle/store
// phases and co-resident blocks stay phase-locked. R6 uses 2048 PERSISTENT
// blocks, each pipelining spans of 32 segments:
//   barrier -> ds_write data(t) [loaded last iter] + table -> barrier ->
//   ISSUE data(t+1) + meta(t+2) loads -> middle(t) -> per-wave stage-out(t)
// Loads are in flight across the entire middle+stage-out window (T14
// issue-early/write-late); metadata is pipelined 2 spans ahead so address
// chains never sit on the critical path. Stage-out is per-wave (wave reads
// only LDS its own lanes wrote -> no third barrier; lgkmcnt fence instead).
// ---------------------------------------------------------------------------

#define GSEG   16                     // lanes per segment group
#define SPG    2                      // segments per group
#define SBLOCK 256                    // threads per block
#define SEGS_B 32                     // segments per span
#define CAPF   1664                   // max stageable span (floats); uniform=1600
#define GRID_C 2048                   // persistent grid (256 CU x 8)

// Kernel A: per-block (256-wide) exclusive scan of counts; block totals out.
__global__ __launch_bounds__(256) void scan_local_kernel(
    const int* __restrict__ counts, int n_seg,
    int* __restrict__ local_scan, int* __restrict__ block_sums) {
    __shared__ int sm[256];
    const int t = threadIdx.x;
    const int g = blockIdx.x * 256 + t;
    const int v = (g < n_seg) ? counts[g] : 0;
    sm[t] = v;
    __syncthreads();
    for (int off = 1; off < 256; off <<= 1) {
        int y = (t >= off) ? sm[t - off] : 0;
        __syncthreads();
        sm[t] += y;
        __syncthreads();
    }
    if (g < n_seg) local_scan[g] = sm[t] - v;   // exclusive within block
    if (t == 255) block_sums[blockIdx.x] = sm[255];
}

// Kernel B: single-block exclusive scan of block_sums in place.
__global__ __launch_bounds__(256) void scan_bsums_kernel(
    int* __restrict__ bsum, int nb) {
    __shared__ int sm[256];
    const int t = threadIdx.x;
    const int per = (nb + 255) >> 8;
    const int beg = t * per;
    const int end = (beg + per < nb) ? beg + per : nb;
    int tot = 0;
    for (int j = beg; j < end; ++j) tot += bsum[j];
    sm[t] = tot;
    __syncthreads();
    for (int off = 1; off < 256; off <<= 1) {
        int y = (t >= off) ? sm[t - off] : 0;
        __syncthreads();
        sm[t] += y;
        __syncthreads();
    }
    int run = sm[t] - tot;
    for (int j = beg; j < end; ++j) {
        int v = bsum[j];
        bsum[j] = run;
        run += v;
    }
}

// Kernel C: persistent pipelined segmented softmax.
__global__ __launch_bounds__(SBLOCK, 4) void seg_softmax_kernel(
    const float* __restrict__ scores,
    const int* __restrict__ local_scan, const int* __restrict__ bsum,
    float* __restrict__ out, int n_seg, int total) {

    __shared__ float buf[CAPF];
    __shared__ int   tab[SEGS_B + 1];

    const int tid    = threadIdx.x;
    const int stride = gridDim.x;
    const int nspans = (n_seg + SEGS_B - 1) / SEGS_B;

    int t = blockIdx.x;
    if (t >= nspans) return;          // block-uniform

    // Absolute element offset of segment s (clamped past the end).
    #define SEG_START(s) (((s) < n_seg) ? (local_scan[(s)] + bsum[(s) >> 8]) : total)

    const int lane = tid & 63;
    const int wv   = tid >> 6;        // wave 0..3
    const int p    = tid & (GSEG - 1);
    const int grp  = tid >> 4;        // group 0..15

    // ---- prologue: meta(t) [wait], issue data(t), meta(t+1) in flight ----
    int curb0 = SEG_START(t * SEGS_B);
    int curb1 = SEG_START(t * SEGS_B + SEGS_B);
    int tregA = 0;
    if (tid <= SEGS_B) tregA = SEG_START(t * SEGS_B + tid);
    bool fitCur = ((curb1 - curb0) <= CAPF) && ((curb0 & 3) == 0);

    float4 r0, r1;
    float  rt;
    if (fitCur) {
        const int nvec = (curb1 - curb0) >> 2;
        const int rem  = (curb1 - curb0) & 3;
        const float4* __restrict__ src = (const float4*)(scores + curb0);
        if (tid < nvec)          r0 = src[tid];
        if (tid + SBLOCK < nvec) r1 = src[tid + SBLOCK];
        if (tid < rem)           rt = scores[curb0 + (nvec << 2) + tid];
    }

    int tn = t + stride;
    int nxtb0 = 0, nxtb1 = 0, tregB = 0;
    if (tn < nspans) {
        nxtb0 = SEG_START(tn * SEGS_B);
        nxtb1 = SEG_START(tn * SEGS_B + SEGS_B);
        if (tid <= SEGS_B) tregB = SEG_START(tn * SEGS_B + tid);
    }

    while (true) {
        __syncthreads();                              // [B1] data(t) arrived; prev stage-out LDS reads done

        // ---- stage data(t) + table into LDS ----
        const int spanf = curb1 - curb0;
        if (fitCur) {
            const int nvec = spanf >> 2;
            const int rem  = spanf & 3;
            float4* d = (float4*)buf;
            if (tid < nvec)          d[tid] = r0;
            if (tid + SBLOCK < nvec) d[tid + SBLOCK] = r1;
            if (tid < rem)           buf[(nvec << 2) + tid] = rt;
        }
        if (tid <= SEGS_B) tab[tid] = tregA;
        __syncthreads();                              // [B2] cheap: no global loads outstanding

        // ---- issue data(t+1) + meta(t+2): in flight over middle+stage-out ----
        const bool haveNext = (tn < nspans);
        const bool fitNext  = haveNext &&
                              ((nxtb1 - nxtb0) <= CAPF) && ((nxtb0 & 3) == 0);
        if (fitNext) {
            const int nv2  = (nxtb1 - nxtb0) >> 2;
            const int rem2 = (nxtb1 - nxtb0) & 3;
            const float4* __restrict__ src = (const float4*)(scores + nxtb0);
            if (tid < nv2)          r0 = src[tid];
            if (tid + SBLOCK < nv2) r1 = src[tid + SBLOCK];
            if (tid < rem2)         rt = scores[nxtb0 + (nv2 << 2) + tid];
        }
        const int tnn = tn + stride;
        int nnb0 = 0, nnb1 = 0, tregC = 0;
        if (tnn < nspans) {
            nnb0 = SEG_START(tnn * SEGS_B);
            nnb1 = SEG_START(tnn * SEGS_B + SEGS_B);
            if (tid <= SEGS_B) tregC = SEG_START(tnn * SEGS_B + tid);
        }

        if (fitCur) {
            // ---- middle: 16-lane group x 2 segments, registers + shfl ----
            #pragma unroll
            for (int q = 0; q < SPG; ++q) {
                const int ls = grp * SPG + q;
                const int s0 = tab[ls] - curb0;
                const int c  = tab[ls + 1] - tab[ls];
                if (c <= 0) continue;
                if (c <= 4 * GSEG) {
                    const int i0 = p, i1 = p + GSEG, i2 = p + 2 * GSEG, i3 = p + 3 * GSEG;
                    float v0 = -INFINITY, v1 = -INFINITY, v2 = -INFINITY, v3 = -INFINITY;
                    if (i0 < c) v0 = buf[s0 + i0];
                    if (i1 < c) v1 = buf[s0 + i1];
                    if (i2 < c) v2 = buf[s0 + i2];
                    if (i3 < c) v3 = buf[s0 + i3];

                    float m = fmaxf(fmaxf(v0, v1), fmaxf(v2, v3));
                    #pragma unroll
                    for (int off = 1; off < GSEG; off <<= 1)
                        m = fmaxf(m, __shfl_xor(m, off, GSEG));

                    const float e0 = __expf(v0 - m);   // exp(-INF - m) == 0
                    const float e1 = __expf(v1 - m);
                    const float e2 = __expf(v2 - m);
                    const float e3 = __expf(v3 - m);
                    float s = (e0 + e1) + (e2 + e3);
                    #pragma unroll
                    for (int off = 1; off < GSEG; off <<= 1)
                        s += __shfl_xor(s, off, GSEG);

                    const float inv = __builtin_amdgcn_rcpf(s);
                    if (i0 < c) buf[s0 + i0] = e0 * inv;
                    if (i1 < c) buf[s0 + i1] = e1 * inv;
                    if (i2 < c) buf[s0 + i2] = e2 * inv;
                    if (i3 < c) buf[s0 + i3] = e3 * inv;
                } else {
                    // big segment still resident in LDS: strided 3-pass
                    float m = -INFINITY;
                    for (int j = p; j < c; j += GSEG)
                        m = fmaxf(m, buf[s0 + j]);
                    #pragma unroll
                    for (int off = 1; off < GSEG; off <<= 1)
                        m = fmaxf(m, __shfl_xor(m, off, GSEG));
                    float s = 0.0f;
                    for (int j = p; j < c; j += GSEG) {
                        const float e = __expf(buf[s0 + j] - m);
                        buf[s0 + j] = e;
                        s += e;
                    }
                    #pragma unroll
                    for (int off = 1; off < GSEG; off <<= 1)
                        s += __shfl_xor(s, off, GSEG);
                    const float inv = __builtin_amdgcn_rcpf(s);
                    for (int j = p; j < c; j += GSEG)
                        buf[s0 + j] *= inv;
                }
            }

            // Wave-internal fence: stage-out reads LDS written by this wave's
            // own lanes (wave w's groups own exactly wave w's segments).
            __builtin_amdgcn_wave_barrier();
            __asm__ __volatile__("s_waitcnt lgkmcnt(0)" ::: "memory");
            __builtin_amdgcn_sched_barrier(0);

            // ---- per-wave contiguous float4 stage-out (no 3rd barrier) ----
            const int wseg = wv * (SEGS_B / 4);        // 8 segments per wave
            const int ob   = tab[wseg];
            const int oe   = tab[wseg + (SEGS_B / 4)];
            const int rel  = ob - curb0;
            const int len  = oe - ob;
            if (((ob | rel) & 3) == 0) {
                const int nv = len >> 2;
                const int rm = len & 3;
                float4* __restrict__ dst = (float4*)(out + ob);
                const float4* __restrict__ s4 = (const float4*)(buf + rel);
                for (int j = lane; j < nv; j += 64) dst[j] = s4[j];
                if (lane < rm) out[ob + (nv << 2) + lane] = buf[rel + (nv << 2) + lane];
            } else {
                for (int j = lane; j < len; j += 64) out[ob + j] = buf[rel + j];
            }
        } else {
            // ---- slow path: span too big / unaligned -> global 3-pass ----
            #pragma unroll
            for (int q = 0; q < SPG; ++q) {
                const int ls = grp * SPG + q;
                const int st = tab[ls];
                const int c  = tab[ls + 1] - st;
                if (c <= 0) continue;
                float m = -INFINITY;
                for (int j = p; j < c; j += GSEG)
                    m = fmaxf(m, scores[st + j]);
                #pragma unroll
                for (int off = 1; off < GSEG; off <<= 1)
                    m = fmaxf(m, __shfl_xor(m, off, GSEG));
                float s = 0.0f;
                for (int j = p; j < c; j += GSEG)
                    s += __expf(scores[st + j] - m);
                #pragma unroll
                for (int off = 1; off < GSEG; off <<= 1)
                    s += __shfl_xor(s, off, GSEG);
                const float inv = __builtin_amdgcn_rcpf(s);
                for (int j = p; j < c; j += GSEG)
                    out[st + j] = __expf(scores[st + j] - m) * inv;
            }
        }

        // ---- rotate pipeline state ----
        if (!haveNext) break;
        t = tn; tn = tnn;
        curb0 = nxtb0; curb1 = nxtb1; tregA = tregB;
        nxtb0 = nnb0;  nxtb1 = nnb1;  tregB = tregC;
        fitCur = fitNext;
    }
    #undef SEG_START
}

extern "C" void kernel_launch(void* const* d_in, const int* in_sizes, int n_in,
                              void* d_out, int out_size, void* d_ws, size_t ws_size,
                              hipStream_t stream) {
    const float* scores = (const float*)d_in[0];
    const int*   counts = (const int*)d_in[1];
    float* out = (float*)d_out;
    const int n_seg = in_sizes[1];
    const int total = in_sizes[0];

    // Workspace layout: [n_seg] local exclusive scan | [nblocksA] block sums
    int* local_scan = (int*)d_ws;
    const int nblocksA = (n_seg + 255) / 256;
    int* block_sums = local_scan + n_seg;

    scan_local_kernel<<<nblocksA, 256, 0, stream>>>(counts, n_seg, local_scan, block_sums);
    scan_bsums_kernel<<<1, 256, 0, stream>>>(block_sums, nblocksA);

    const int nspans = (n_seg + SEGS_B - 1) / SEGS_B;
    const int grid   = (nspans < GRID_C) ? nspans : GRID_C;
    seg_softmax_kernel<<<grid, SBLOCK, 0, stream>>>(
        scores, local_scan, block_sums, out, n_seg, total);
}